// Round 3
// baseline (692.570 us; speedup 1.0000x reference)
//
#include <hip/hip_runtime.h>

#define QLEN 256
#define DDIM 64
#define WOUT 32

typedef __bf16 b8v __attribute__((ext_vector_type(8)));
typedef float f4v __attribute__((ext_vector_type(4)));

__device__ __forceinline__ f4v MFMA(b8v a, b8v b, f4v c) {
  return __builtin_amdgcn_mfma_f32_16x16x32_bf16(a, b, c, 0, 0, 0);
}
__device__ __forceinline__ float sigmoidf_(float x) { return 1.0f/(1.0f+__expf(-x)); }
__device__ __forceinline__ float tanhf_(float x)    { return 1.0f - 2.0f/(__expf(2.0f*x)+1.0f); }

// ---------------- Kernel 1: Kalman scan (256 steps) ----------------
// 256 WGs x 512 threads (8 waves); each WG owns 8 batch rows (M=16 tile, rows 8..15 zero).
// Conv lag-split: lags 1-4 (24 frags) issue in the rot2/transcendental phase (off the
// critical path); only lag-0 (6 frags) runs post-feat. hi waves (4-7) own 15 lag1-4
// frags and write PART before B2; lo waves (0-3) own 9 lag1-4 + 6 lag0 frags.
__global__ __launch_bounds__(512, 2)
void k_kalman(const float* __restrict__ x_in,
              const float* __restrict__ conv_w, const float* __restrict__ conv_b,
              const float* __restrict__ fc1_w,  const float* __restrict__ fc1_b,
              const float* __restrict__ fc2_w,  const float* __restrict__ fc2_b,
              const float* __restrict__ rot1_w, const float* __restrict__ rot1_b,
              const float* __restrict__ rot2_w, const float* __restrict__ rot2_b,
              float* __restrict__ out)
{
  __shared__ __align__(16) __bf16 SMB[24064];
  __shared__ __align__(16) float  SMF[3584];
  const int tid = threadIdx.x;
  const int w  = tid >> 6;      // wave 0..7
  const int l  = tid & 63;
  const int lr = l & 15;
  const int lg = l >> 4;
  const int wg = blockIdx.x;
  const bool lo = (w < 4);

  __bf16* XPB  = SMB;            // [16][72]  x_post bf16 shadow (A-operand)
  __bf16* T1   = SMB + 1152;     // [16][144] relu(rot1)   (stride 144: conflict-free b16 writes)
  __bf16* TC   = SMB + 3456;     // [16][144] relu(conv)
  __bf16* T2   = SMB + 5760;     // [16][144] relu(fc1)
  __bf16* FEAT = SMB + 8064;     // [5][16][200] feat ring
  float*  XPF  = SMF;            // [8][64] x_post fp32 (master state)
  float*  XPRI = SMF + 512;      // [8][64]
  float*  INV  = SMF + 1024;     // [8][64]
  float*  PART = SMF + 1536;     // [8 tiles][16 lr][16] conv lag1-4 partials from hi waves

  for (int i = tid; i < 24064; i += 512) SMB[i] = (__bf16)0.0f;
  for (int i = tid; i < 3584;  i += 512) SMF[i] = 0.0f;

  const int hcol = 16*w + lr;
  const int tlo  = 2*(w & 3);          // this pair's N-tile base (tiles tlo, tlo+1)

  // ---- register-resident B fragments (weights, bf16) ----
  // conv frag map: frag f = L*6+q (L=lag, q=K-subtile of 32 in 192).
  //   lo wave: i 0..8 -> f=6+i (Y phase), i 9..14 -> f=i-9 (lag0, Z phase)
  //   hi wave: i 0..14 -> f=15+i (Y phase)
  b8v r1B[2], f1B[4], f2B[4], cvB[15][2];
  #pragma unroll
  for (int q = 0; q < 2; ++q)
    #pragma unroll
    for (int j = 0; j < 8; ++j)
      r1B[q][j] = (__bf16)rot1_w[hcol*64 + q*32 + lg*8 + j];
  #pragma unroll
  for (int q = 0; q < 4; ++q)
    #pragma unroll
    for (int j = 0; j < 8; ++j)
      f1B[q][j] = (__bf16)fc1_w[hcol*128 + q*32 + lg*8 + j];
  {
    const int h2 = lo ? hcol : 0;   // fc2_w has 64 rows
    #pragma unroll
    for (int q = 0; q < 4; ++q)
      #pragma unroll
      for (int j = 0; j < 8; ++j)
        f2B[q][j] = (__bf16)fc2_w[h2*128 + q*32 + lg*8 + j];
  }
  #pragma unroll
  for (int i = 0; i < 15; ++i) {
    const int f = lo ? ((i < 9) ? (6+i) : (i-9)) : (15+i);
    const int L = f/6, q = f%6;
    #pragma unroll
    for (int ti = 0; ti < 2; ++ti)
      #pragma unroll
      for (int j = 0; j < 8; ++j)
        cvB[i][ti][j] =
          (__bf16)conv_w[((tlo+ti)*16 + lr)*960 + (q*32 + lg*8 + j)*5 + (4-L)];
  }

  const float b_r1 = rot1_b[hcol];
  const float b_f1 = fc1_b[hcol];
  const float b_f2 = fc2_b[lo ? hcol : 0];
  const float bc0  = conv_b[tlo*16 + lr];
  const float bc1  = conv_b[(tlo+1)*16 + lr];
  const float r2w00 = rot2_w[l],       r2w01 = rot2_w[64 + l];
  const float r2w10 = rot2_w[128 + l], r2w11 = rot2_w[192 + l];
  const float rb0 = rot2_b[0], rb1 = rot2_b[1];
  const float PI_F = 3.14159274f;

  const float* xptr = x_in + ((long)(wg*8 + w)*QLEN)*DDIM + l;
  float y_cur = xptr[0];
  float y_prv = y_cur;
  int slot = 0;

  __syncthreads();

  for (int t = 0; t < QLEN; ++t) {
    // ---- X: t1 = relu(x_post @ rot1_w^T + b) ----
    {
      b8v a0 = *(const b8v*)&XPB[lr*72      + lg*8];
      b8v a1 = *(const b8v*)&XPB[lr*72 + 32 + lg*8];
      f4v C = {};
      C = MFMA(a0, r1B[0], C);
      C = MFMA(a1, r1B[1], C);
      #pragma unroll
      for (int r = 0; r < 4; ++r) {
        float v = C[r] + b_r1; v = v > 0.f ? v : 0.f;
        T1[(lg*4+r)*144 + hcol] = (__bf16)v;
      }
    }
    __syncthreads();   // B1

    // ---- Y: conv lag1-4 partials (independent) + rot2 reduce + rotation + feat ----
    f4v C0a = {}, C0b = {}, C1a = {}, C1b = {};
    if (lo) {
      #pragma unroll
      for (int i = 0; i < 9; ++i) {
        const int f = 6+i, L = f/6, q = f%6;
        int s5 = slot - L; if (s5 < 0) s5 += 5;
        b8v a = *(const b8v*)&FEAT[s5*3200 + lr*200 + q*32 + lg*8];
        if (i & 1) { C0b = MFMA(a, cvB[i][0], C0b); C1b = MFMA(a, cvB[i][1], C1b); }
        else       { C0a = MFMA(a, cvB[i][0], C0a); C1a = MFMA(a, cvB[i][1], C1a); }
      }
    } else {
      #pragma unroll
      for (int i = 0; i < 15; ++i) {
        const int f = 15+i, L = f/6, q = f%6;
        int s5 = slot - L; if (s5 < 0) s5 += 5;
        b8v a = *(const b8v*)&FEAT[s5*3200 + lr*200 + q*32 + lg*8];
        if (i & 1) { C0b = MFMA(a, cvB[i][0], C0b); C1b = MFMA(a, cvB[i][1], C1b); }
        else       { C0a = MFMA(a, cvB[i][0], C0a); C1a = MFMA(a, cvB[i][1], C1a); }
      }
    }
    // rot2 (in-wave, element e=w) + rotation + innov/diff feat writes
    float y_nxt;
    {
      float t1a = (float)T1[w*144 + l];
      float t1b = (float)T1[w*144 + 64 + l];
      float acc0 = t1a*r2w00 + t1b*r2w01;
      float acc1 = t1a*r2w10 + t1b*r2w11;
      #pragma unroll
      for (int m = 1; m < 64; m <<= 1) {
        acc0 += __shfl_xor(acc0, m, 64);
        acc1 += __shfl_xor(acc1, m, 64);
      }
      float rho = 1.5f * sigmoidf_(acc0 + rb0);
      float phi = PI_F * tanhf_(acc1 + rb1);
      float cc = rho * __cosf(phi);
      float ss = rho * __sinf(phi);
      float lo32 = XPF[w*64 + (l & 31)];
      float hi32 = XPF[w*64 + (l & 31) + 32];
      float xpri = (l < 32) ? (lo32*cc - hi32*ss) : (lo32*ss + hi32*cc);
      float innov = y_cur - xpri;
      float diff  = y_cur - y_prv;
      __bf16* fr = FEAT + slot*3200 + w*200;
      fr[l]       = (__bf16)innov;
      fr[128 + l] = (__bf16)diff;     // xpv slice [64+l] prewritten by P6 of prev step
      XPRI[w*64 + l] = xpri;
      INV [w*64 + l] = innov;
      y_nxt = (t+1 < QLEN) ? xptr[(t+1)*DDIM] : y_cur;
    }
    if (!lo) {   // hi waves: publish lag1-4 partials
      *(f4v*)&PART[(tlo*16 + lr)*16 + 4*lg]     = C0a + C0b;
      *(f4v*)&PART[((tlo+1)*16 + lr)*16 + 4*lg] = C1a + C1b;
    }
    __syncthreads();   // B2

    // ---- Z: conv lag-0 + combine + relu -> TC (lo waves only) ----
    if (lo) {
      #pragma unroll
      for (int i = 9; i < 15; ++i) {
        const int q = i - 9;
        b8v a = *(const b8v*)&FEAT[slot*3200 + lr*200 + q*32 + lg*8];
        if (i & 1) { C0b = MFMA(a, cvB[i][0], C0b); C1b = MFMA(a, cvB[i][1], C1b); }
        else       { C0a = MFMA(a, cvB[i][0], C0a); C1a = MFMA(a, cvB[i][1], C1a); }
      }
      f4v p0 = *(const f4v*)&PART[(tlo*16 + lr)*16 + 4*lg];
      f4v p1 = *(const f4v*)&PART[((tlo+1)*16 + lr)*16 + 4*lg];
      #pragma unroll
      for (int r = 0; r < 4; ++r) {
        float v0 = C0a[r] + C0b[r] + p0[r] + bc0; v0 = v0 > 0.f ? v0 : 0.f;
        float v1 = C1a[r] + C1b[r] + p1[r] + bc1; v1 = v1 > 0.f ? v1 : 0.f;
        TC[(lg*4+r)*144 + tlo*16 + lr]     = (__bf16)v0;
        TC[(lg*4+r)*144 + (tlo+1)*16 + lr] = (__bf16)v1;
      }
    }
    __syncthreads();   // B3

    // ---- P5: fc1 ----
    {
      f4v D0 = {}, D1 = {};
      #pragma unroll
      for (int q = 0; q < 4; ++q) {
        b8v a = *(const b8v*)&TC[lr*144 + q*32 + lg*8];
        if (q & 1) D1 = MFMA(a, f1B[q], D1); else D0 = MFMA(a, f1B[q], D0);
      }
      #pragma unroll
      for (int r = 0; r < 4; ++r) {
        float v = D0[r] + D1[r] + b_f1; v = v > 0.f ? v : 0.f;
        T2[(lg*4+r)*144 + hcol] = (__bf16)v;
      }
    }
    __syncthreads();   // B4

    const int slot_next = (slot == 4) ? 0 : slot + 1;
    // ---- P6: K = sigmoid(fc2), x_post update + feat-xpv prewrite (lo waves) ----
    if (lo) {
      f4v D0 = {}, D1 = {};
      #pragma unroll
      for (int q = 0; q < 4; ++q) {
        b8v a = *(const b8v*)&T2[lr*144 + q*32 + lg*8];
        if (q & 1) D1 = MFMA(a, f2B[q], D1); else D0 = MFMA(a, f2B[q], D0);
      }
      if (lg < 2) {
        #pragma unroll
        for (int r = 0; r < 4; ++r) {
          int e = lg*4 + r;
          float K = sigmoidf_(D0[r] + D1[r] + b_f2);
          float xn = XPRI[e*64 + hcol] + K * INV[e*64 + hcol];
          XPF[e*64 + hcol] = xn;
          XPB[e*72 + hcol] = (__bf16)xn;
          FEAT[slot_next*3200 + e*200 + 64 + hcol] = (__bf16)xn;  // xpv slice of feat(t+1)
        }
      }
    }
    __syncthreads();   // B5

    y_prv = y_cur; y_cur = y_nxt;
    slot = slot_next;
  }

  // stash fp32 x_post into out[b][0][:] (GRU kernel reads then overwrites)
  out[((long)(wg*8 + w)*WOUT)*DDIM + l] = XPF[w*64 + l];
}

// ---------------- Kernel 2: GRU head (32 steps) ----------------
// 128 WGs x 512 threads; each WG owns 16 batch rows (1 M-tile, no padding).
__global__ __launch_bounds__(512, 2)
void k_gru(const float* __restrict__ gru_wih, const float* __restrict__ gru_whh,
           const float* __restrict__ gru_bih, const float* __restrict__ gru_bhh,
           const float* __restrict__ out_w,   const float* __restrict__ out_b,
           float* __restrict__ out)
{
  __shared__ __align__(16) __bf16 CUR[16*72];
  __shared__ __align__(16) __bf16 HB [16*144];
  const int tid = threadIdx.x;
  const int w  = tid >> 6, l = tid & 63, lr = l & 15, lg = l >> 4;
  const int g = blockIdx.x;

  for (int i = tid; i < 16*144; i += 512) HB[i] = (__bf16)0.f;
  for (int i = tid; i < 16*64; i += 512) {
    int e = i >> 6, d = i & 63;
    CUR[e*72 + d] = (__bf16)out[((long)(g*16 + e)*WOUT)*DDIM + d];
  }

  // B-fragments: wave w owns gate-col tiles n = w, w+8, w+16
  b8v fih[3][2], fhh[3][4], fo[4];
  #pragma unroll
  for (int n3 = 0; n3 < 3; ++n3) {
    int row = 16*(w + 8*n3) + lr;
    #pragma unroll
    for (int q = 0; q < 2; ++q)
      #pragma unroll
      for (int j = 0; j < 8; ++j)
        fih[n3][q][j] = (__bf16)gru_wih[row*64 + q*32 + lg*8 + j];
    #pragma unroll
    for (int q = 0; q < 4; ++q)
      #pragma unroll
      for (int j = 0; j < 8; ++j)
        fhh[n3][q][j] = (__bf16)gru_whh[row*128 + q*32 + lg*8 + j];
  }
  {
    int row = 16*(w & 3) + lr;
    #pragma unroll
    for (int q = 0; q < 4; ++q)
      #pragma unroll
      for (int j = 0; j < 8; ++j)
        fo[q][j] = (__bf16)out_w[row*128 + q*32 + lg*8 + j];
  }
  const int jh = 16*w + lr;
  const float b_ir = gru_bih[jh], b_iz = gru_bih[128+jh], b_in = gru_bih[256+jh];
  const float b_hr = gru_bhh[jh], b_hz = gru_bhh[128+jh], b_hn = gru_bhh[256+jh];
  const float b_o  = out_b[16*(w & 3) + lr];
  const int dcol = 16*(w & 3) + lr;
  __syncthreads();

  for (int s = 0; s < WOUT; ++s) {
    f4v cI[3] = {}, cH[3] = {};
    #pragma unroll
    for (int q = 0; q < 2; ++q) {
      b8v a = *(const b8v*)&CUR[lr*72 + q*32 + lg*8];
      #pragma unroll
      for (int n3 = 0; n3 < 3; ++n3) cI[n3] = MFMA(a, fih[n3][q], cI[n3]);
    }
    #pragma unroll
    for (int q = 0; q < 4; ++q) {
      b8v a = *(const b8v*)&HB[lr*144 + q*32 + lg*8];
      #pragma unroll
      for (int n3 = 0; n3 < 3; ++n3) cH[n3] = MFMA(a, fhh[n3][q], cH[n3]);
    }
    __syncthreads();   // all CUR/HB reads done before writes

    #pragma unroll
    for (int r = 0; r < 4; ++r) {
      int e = lg*4 + r;
      float ir = cI[0][r] + b_ir, iz = cI[1][r] + b_iz, in_ = cI[2][r] + b_in;
      float hr = cH[0][r] + b_hr, hz = cH[1][r] + b_hz, hn  = cH[2][r] + b_hn;
      float rr = sigmoidf_(ir + hr);
      float zz = sigmoidf_(iz + hz);
      float nn = tanhf_(in_ + rr*hn);
      float hold = (float)HB[e*144 + jh];
      float hnew = (1.f - zz)*nn + zz*hold;
      HB[e*144 + jh] = (__bf16)hnew;
    }
    __syncthreads();   // h_new complete

    if (w < 4) {
      f4v C0 = {};
      #pragma unroll
      for (int q = 0; q < 4; ++q) {
        b8v a = *(const b8v*)&HB[lr*144 + q*32 + lg*8];
        C0 = MFMA(a, fo[q], C0);
      }
      #pragma unroll
      for (int r = 0; r < 4; ++r) {
        int e = lg*4 + r;
        float cn = (float)CUR[e*72 + dcol] + C0[r] + b_o;
        CUR[e*72 + dcol] = (__bf16)cn;
        out[(((long)(g*16 + e))*WOUT + s)*DDIM + dcol] = cn;
      }
    }
    __syncthreads();
  }
}

extern "C" void kernel_launch(void* const* d_in, const int* in_sizes, int n_in,
                              void* d_out, int out_size, void* d_ws, size_t ws_size,
                              hipStream_t stream) {
  (void)in_sizes; (void)n_in; (void)d_ws; (void)ws_size; (void)out_size;
  const float* x_in   = (const float*)d_in[0];
  const float* conv_w = (const float*)d_in[2];
  const float* conv_b = (const float*)d_in[3];
  const float* fc1_w  = (const float*)d_in[4];
  const float* fc1_b  = (const float*)d_in[5];
  const float* fc2_w  = (const float*)d_in[6];
  const float* fc2_b  = (const float*)d_in[7];
  const float* rot1_w = (const float*)d_in[8];
  const float* rot1_b = (const float*)d_in[9];
  const float* rot2_w = (const float*)d_in[10];
  const float* rot2_b = (const float*)d_in[11];
  const float* gwih   = (const float*)d_in[12];
  const float* gwhh   = (const float*)d_in[13];
  const float* gbih   = (const float*)d_in[14];
  const float* gbhh   = (const float*)d_in[15];
  const float* ow     = (const float*)d_in[16];
  const float* ob     = (const float*)d_in[17];
  float* out = (float*)d_out;

  k_kalman<<<256, 512, 0, stream>>>(x_in, conv_w, conv_b, fc1_w, fc1_b,
                                    fc2_w, fc2_b, rot1_w, rot1_b,
                                    rot2_w, rot2_b, out);
  k_gru<<<128, 512, 0, stream>>>(gwih, gwhh, gbih, gbhh, ow, ob, out);
}